// Round 1
// baseline (483.385 us; speedup 1.0000x reference)
//
#include <hip/hip_runtime.h>
#include <math.h>

#define G 2
#define BB 2
#define L 1024
#define DM 256
#define DI 512
#define DS 16
#define DR 16
#define CH 64
#define CL 16              // L / CH
#define RTOT (G*BB*L)      // 4096 rows per layer-step

__device__ __forceinline__ float silu_f(float x) { return x / (1.f + __expf(-x)); }

// ---------------------------------------------------------------------------
// Generic fp32 GEMM: C[r][n] = sum_k A[r*lda+k] * W[lay][n][k]
// lay = (r>>11)*2 + step   (rows 0..2047 are chain g=0, 2048..4095 chain g=1)
// mode 0: plain store to C (ldc)
// mode 1: softplus(acc + bias[lay][n]) -> C
// mode 2: final out_proj scatter: fwd rows -> out[b,l,0:256], bwd rows ->
//         out[b,1023-l,256:512]
// ---------------------------------------------------------------------------
__global__ __launch_bounds__(256) void gemm64(
    const float* __restrict__ A, int lda, int K,
    const float* __restrict__ W, int Nout, int step,
    float* __restrict__ C, int ldc,
    const float* __restrict__ bias, int mode,
    float* __restrict__ outf)
{
    __shared__ float As[16][68];
    __shared__ float Bs[16][68];
    const int row0 = blockIdx.y * 64;
    const int col0 = blockIdx.x * 64;
    const int g    = row0 >> 11;
    const int lay  = g * 2 + step;
    const float* Wg = W + (size_t)lay * Nout * K;
    const int t  = threadIdx.x;
    const int tx = t & 15, ty = t >> 4;

    float acc[4][4];
    #pragma unroll
    for (int i = 0; i < 4; i++)
        #pragma unroll
        for (int j = 0; j < 4; j++) acc[i][j] = 0.f;

    for (int k0 = 0; k0 < K; k0 += 16) {
        #pragma unroll
        for (int i = 0; i < 4; i++) {
            int li = t + 256 * i;
            int rr = li >> 4, kk = li & 15;
            As[kk][rr] = A[(size_t)(row0 + rr) * lda + k0 + kk];
            float wv = 0.f;
            if (col0 + rr < Nout) wv = Wg[(size_t)(col0 + rr) * K + k0 + kk];
            Bs[kk][rr] = wv;
        }
        __syncthreads();
        #pragma unroll
        for (int kk = 0; kk < 16; kk++) {
            float av[4], bv[4];
            #pragma unroll
            for (int i = 0; i < 4; i++) av[i] = As[kk][ty * 4 + i];
            #pragma unroll
            for (int j = 0; j < 4; j++) bv[j] = Bs[kk][tx * 4 + j];
            #pragma unroll
            for (int i = 0; i < 4; i++)
                #pragma unroll
                for (int j = 0; j < 4; j++) acc[i][j] += av[i] * bv[j];
        }
        __syncthreads();
    }

    #pragma unroll
    for (int i = 0; i < 4; i++) {
        int r = row0 + ty * 4 + i;
        #pragma unroll
        for (int j = 0; j < 4; j++) {
            int col = col0 + tx * 4 + j;
            if (col >= Nout) continue;
            float v = acc[i][j];
            if (mode == 1) {
                v += bias[(size_t)lay * DI + col];
                v = (v > 20.f) ? v : log1pf(__expf(v));
                C[(size_t)r * ldc + col] = v;
            } else if (mode == 2) {
                int b = (r >> 10) & 1, l = r & 1023;
                size_t dst;
                if (g == 0) dst = ((size_t)(b * 1024 + l) * 512) + col;
                else        dst = ((size_t)(b * 1024 + (1023 - l)) * 512) + 256 + col;
                outf[dst] = v;
            } else {
                C[(size_t)r * ldc + col] = v;
            }
        }
    }
}

// ---------------------------------------------------------------------------
// Depthwise causal conv (K=4) + bias + silu on the xc half of XZ.
// ---------------------------------------------------------------------------
__global__ __launch_bounds__(256) void conv_silu(
    const float* __restrict__ XZ, const float* __restrict__ cw,
    const float* __restrict__ cb, float* __restrict__ XC, int step)
{
    int id = blockIdx.x * 256 + threadIdx.x;   // id = r*512 + d
    int d = id & 511;
    int r = id >> 9;
    int g = r >> 11;
    int l = r & 1023;
    int lay = g * 2 + step;
    const float* w = cw + ((size_t)lay * 512 + d) * 4;
    float acc = cb[(size_t)lay * 512 + d];
    #pragma unroll
    for (int k = 0; k < 4; k++) {
        int ls = l - 3 + k;
        if (ls >= 0) acc += w[k] * XZ[(size_t)(r - 3 + k) * 1024 + d];
    }
    XC[id] = silu_f(acc);
}

// ---------------------------------------------------------------------------
// Scan phase A: per (gb, chunk, d) compute prod(dA) and h_end with h0=0.
// ---------------------------------------------------------------------------
__global__ __launch_bounds__(512) void scanA(
    const float* __restrict__ DTb, const float* __restrict__ XCb,
    const float* __restrict__ DBLb, const float* __restrict__ A_log,
    float* __restrict__ Aprod, float* __restrict__ Hend, int step)
{
    __shared__ float Bsh[CL][DS];
    int blk = blockIdx.x;           // (gb)*CH + c
    int c  = blk & (CH - 1);
    int gb = blk >> 6;              // g*BB + b in [0,4)
    int g  = gb >> 1;
    int lay = g * 2 + step;
    int d = threadIdx.x;
    int r0 = gb * L + c * CL;

    if (threadIdx.x < CL * DS) {
        int tt = threadIdx.x >> 4, s = threadIdx.x & 15;
        Bsh[tt][s] = DBLb[(size_t)(r0 + tt) * 48 + 16 + s];
    }
    __syncthreads();

    float a[DS], h[DS], ap[DS];
    const float* al = A_log + ((size_t)lay * DI + d) * DS;
    #pragma unroll
    for (int s = 0; s < DS; s++) { a[s] = -__expf(al[s]); h[s] = 0.f; ap[s] = 1.f; }

    for (int tt = 0; tt < CL; tt++) {
        int r = r0 + tt;
        float dt = DTb[(size_t)r * DI + d];
        float xc = XCb[(size_t)r * DI + d];
        float dx = dt * xc;
        #pragma unroll
        for (int s = 0; s < DS; s++) {
            float da = __expf(dt * a[s]);
            h[s] = da * h[s] + dx * Bsh[tt][s];
            ap[s] *= da;
        }
    }
    size_t base = ((size_t)(gb * DI + d) * CH + c) * DS;
    #pragma unroll
    for (int s = 0; s < DS; s++) { Aprod[base + s] = ap[s]; Hend[base + s] = h[s]; }
}

// ---------------------------------------------------------------------------
// Combine: serial exclusive scan over the 64 chunks, per (gb,d,s) lane.
// Overwrites H (h_end) in place with h_init for each chunk.
// ---------------------------------------------------------------------------
__global__ __launch_bounds__(256) void scanCombine(
    const float* __restrict__ Aprod, float* __restrict__ H)
{
    int idx = blockIdx.x * 256 + threadIdx.x;  // (gb*DI+d)*DS + s, 32768 total
    int s  = idx & 15;
    int gd = idx >> 4;
    size_t base = (size_t)gd * CH * DS + s;
    float h = 0.f;
    for (int c = 0; c < CH; c++) {
        size_t o = base + (size_t)c * DS;
        float aP = Aprod[o];
        float e  = H[o];
        H[o] = h;              // now h_init for chunk c
        h = aP * h + e;
    }
}

// ---------------------------------------------------------------------------
// Scan phase B: replay chunk with h_init, emit y, fuse +xc*D and *silu(z).
// ---------------------------------------------------------------------------
__global__ __launch_bounds__(512) void scanB(
    const float* __restrict__ DTb, const float* __restrict__ XCb,
    const float* __restrict__ DBLb, const float* __restrict__ XZ,
    const float* __restrict__ A_log, const float* __restrict__ Dp,
    const float* __restrict__ Hinit, float* __restrict__ Yb, int step)
{
    __shared__ float Bsh[CL][DS];
    __shared__ float Csh[CL][DS];
    int blk = blockIdx.x;
    int c  = blk & (CH - 1);
    int gb = blk >> 6;
    int g  = gb >> 1;
    int lay = g * 2 + step;
    int d = threadIdx.x;
    int r0 = gb * L + c * CL;

    if (threadIdx.x < CL * DS) {
        int tt = threadIdx.x >> 4, s = threadIdx.x & 15;
        Bsh[tt][s] = DBLb[(size_t)(r0 + tt) * 48 + 16 + s];
        Csh[tt][s] = DBLb[(size_t)(r0 + tt) * 48 + 32 + s];
    }
    __syncthreads();

    float a[DS], h[DS];
    const float* al = A_log + ((size_t)lay * DI + d) * DS;
    size_t base = ((size_t)(gb * DI + d) * CH + c) * DS;
    #pragma unroll
    for (int s = 0; s < DS; s++) { a[s] = -__expf(al[s]); h[s] = Hinit[base + s]; }
    float Dv = Dp[(size_t)lay * DI + d];

    for (int tt = 0; tt < CL; tt++) {
        int r = r0 + tt;
        float dt = DTb[(size_t)r * DI + d];
        float xc = XCb[(size_t)r * DI + d];
        float dx = dt * xc;
        float y = 0.f;
        #pragma unroll
        for (int s = 0; s < DS; s++) {
            float da = __expf(dt * a[s]);
            h[s] = da * h[s] + dx * Bsh[tt][s];
            y += h[s] * Csh[tt][s];
        }
        y += xc * Dv;
        float z = XZ[(size_t)r * 1024 + 512 + d];
        y *= silu_f(z);
        Yb[(size_t)r * DI + d] = y;
    }
}

// ---------------------------------------------------------------------------
// Build the G=2 batched input: chain 0 = x, chain 1 = x time-reversed.
// ---------------------------------------------------------------------------
__global__ __launch_bounds__(256) void initX(
    const float* __restrict__ x, float* __restrict__ X0)
{
    int id = blockIdx.x * 256 + threadIdx.x;   // RTOT*DM total
    int m = id & 255;
    int r = id >> 8;
    int g = r >> 11, b = (r >> 10) & 1, l = r & 1023;
    int sl = g ? (1023 - l) : l;
    X0[id] = x[(size_t)(b * 1024 + sl) * 256 + m];
}

extern "C" void kernel_launch(void* const* d_in, const int* in_sizes, int n_in,
                              void* d_out, int out_size, void* d_ws, size_t ws_size,
                              hipStream_t stream)
{
    const float* x        = (const float*)d_in[0];
    const float* in_proj  = (const float*)d_in[1];
    const float* conv_w   = (const float*)d_in[2];
    const float* conv_b   = (const float*)d_in[3];
    const float* x_proj   = (const float*)d_in[4];
    const float* dt_proj  = (const float*)d_in[5];
    const float* dt_bias  = (const float*)d_in[6];
    const float* A_log    = (const float*)d_in[7];
    const float* Dp       = (const float*)d_in[8];
    const float* out_proj = (const float*)d_in[9];
    float* out = (float*)d_out;

    float* w = (float*)d_ws;
    size_t o = 0;
    float* X0    = w + o; o += (size_t)RTOT * DM;        // 1M
    float* X1    = w + o; o += (size_t)RTOT * DM;        // 1M
    float* XZ    = w + o; o += (size_t)RTOT * 1024;      // 4M
    float* XCb   = w + o; o += (size_t)RTOT * DI;        // 2M
    float* DBLb  = w + o; o += (size_t)RTOT * 48;
    float* DTb   = w + o; o += (size_t)RTOT * DI;        // 2M
    float* Yb    = w + o; o += (size_t)RTOT * DI;        // 2M
    float* Aprod = w + o; o += (size_t)G * BB * DI * CH * DS;  // 2M
    float* Hend  = w + o; o += (size_t)G * BB * DI * CH * DS;  // 2M
    (void)ws_size; (void)in_sizes; (void)n_in; (void)out_size;

    initX<<<RTOT * DM / 256, 256, 0, stream>>>(x, X0);

    for (int step = 0; step < 2; step++) {
        const float* Xin = step ? X1 : X0;
        // xz = x @ W_in^T   (4096 x 1024, K=256)
        gemm64<<<dim3(1024 / 64, RTOT / 64), 256, 0, stream>>>(
            Xin, DM, DM, in_proj, 2 * DI, step, XZ, 1024, nullptr, 0, nullptr);
        // causal conv + silu
        conv_silu<<<RTOT * DI / 256, 256, 0, stream>>>(XZ, conv_w, conv_b, XCb, step);
        // dbl = xc @ W_x^T  (4096 x 48, K=512)
        gemm64<<<dim3(1, RTOT / 64), 256, 0, stream>>>(
            XCb, DI, DI, x_proj, 48, step, DBLb, 48, nullptr, 0, nullptr);
        // dt = softplus(dtin @ W_dt^T + b)  (4096 x 512, K=16)
        gemm64<<<dim3(512 / 64, RTOT / 64), 256, 0, stream>>>(
            DBLb, 48, DR, dt_proj, DI, step, DTb, DI, dt_bias, 1, nullptr);
        // chunked selective scan
        scanA<<<G * BB * CH, 512, 0, stream>>>(DTb, XCb, DBLb, A_log, Aprod, Hend, step);
        scanCombine<<<(G * BB * DI * DS) / 256, 256, 0, stream>>>(Aprod, Hend);
        scanB<<<G * BB * CH, 512, 0, stream>>>(DTb, XCb, DBLb, XZ, A_log, Dp, Hend, Yb, step);
        // out = y @ W_out^T  (4096 x 256, K=512)
        if (step == 0)
            gemm64<<<dim3(DM / 64, RTOT / 64), 256, 0, stream>>>(
                Yb, DI, DI, out_proj, DM, step, X1, DM, nullptr, 0, nullptr);
        else
            gemm64<<<dim3(DM / 64, RTOT / 64), 256, 0, stream>>>(
                Yb, DI, DI, out_proj, DM, step, nullptr, 0, nullptr, 2, out);
    }
}